// Round 1
// baseline (539.054 us; speedup 1.0000x reference)
//
#include <hip/hip_runtime.h>

#define NDIM 128

typedef __attribute__((ext_vector_type(8))) short s16x8;
typedef __attribute__((ext_vector_type(4))) float f32x4;

// fp32 -> bf16 (RNE) and back, bit-level
__device__ __forceinline__ unsigned short f2bf(float f) {
    unsigned u = __float_as_uint(f);
    u += 0x7FFFu + ((u >> 16) & 1u);
    return (unsigned short)(u >> 16);
}
__device__ __forceinline__ float bf2f(unsigned short h) {
    return __uint_as_float((unsigned)h << 16);
}

// ---------------- edge-index normalization ----------------
__global__ __launch_bounds__(256) void detect_kernel(
    const int* __restrict__ raw, int* __restrict__ flag, int E) {
    __shared__ int any_nz;
    if (threadIdx.x == 0) any_nz = 0;
    __syncthreads();
    int local = 0;
    const int samples = (E < 4096) ? E : 4096;
#pragma unroll
    for (int j = 0; j < 16; ++j) {
        int i = threadIdx.x * 16 + j;
        if (i < samples) local |= raw[2 * i + 1];
    }
    if (local) atomicOr(&any_nz, 1);
    __syncthreads();
    if (threadIdx.x == 0) *flag = any_nz;   // nonzero -> int32 layout
}

// convert + fused degree histogram
__global__ void convert_kernel(const int* __restrict__ raw, const int* __restrict__ flag,
                               int* __restrict__ idx, int* __restrict__ deg, int E) {
    int i = blockIdx.x * 256 + threadIdx.x;
    if (i >= 2 * E) return;
    int v = (*flag == 0) ? raw[2 * i] : raw[i];
    idx[i] = v;
    if (i >= E) atomicAdd(&deg[v], 1);   // dst words
}

__global__ __launch_bounds__(256) void deg_reduce_kernel(
    const int* __restrict__ deg, int* __restrict__ partials, int n) {
    const int base = blockIdx.x * 1024;
    const int tid = threadIdx.x;
    int s = 0;
#pragma unroll
    for (int j = 0; j < 4; ++j) {
        int i = base + tid * 4 + j;
        if (i < n) s += deg[i];
    }
#pragma unroll
    for (int off = 32; off; off >>= 1) s += __shfl_down(s, off);
    __shared__ int ws[4];
    if ((tid & 63) == 0) ws[tid >> 6] = s;
    __syncthreads();
    if (tid == 0) partials[blockIdx.x] = ws[0] + ws[1] + ws[2] + ws[3];
}

__global__ void scan_partials_kernel(int* __restrict__ partials, int nb,
                                     int* __restrict__ row_start, int n) {
    __shared__ int sh[1024];
    const int tid = threadIdx.x;
    int v = (tid < nb) ? partials[tid] : 0;
    sh[tid] = v;
    __syncthreads();
    for (int off = 1; off < 1024; off <<= 1) {
        int a = sh[tid];
        int b = (tid >= off) ? sh[tid - off] : 0;
        __syncthreads();
        sh[tid] = a + b;
        __syncthreads();
    }
    if (tid < nb) partials[tid] = (tid == 0) ? 0 : sh[tid - 1];
    if (tid == 0) row_start[n] = sh[1023];
}

__global__ __launch_bounds__(256) void deg_downsweep_kernel(
    const int* __restrict__ deg, const int* __restrict__ partials,
    int* __restrict__ row_start, int* __restrict__ cursor,
    float* __restrict__ inv_deg, int n) {
    const int base = blockIdx.x * 1024;
    const int tid = threadIdx.x;
    const int i0 = base + tid * 4;
    int d[4];
    int s = 0;
#pragma unroll
    for (int j = 0; j < 4; ++j) {
        int i = i0 + j;
        d[j] = (i < n) ? deg[i] : 0;
        s += d[j];
    }
    const int lane = tid & 63;
    int incl = s;
#pragma unroll
    for (int off = 1; off < 64; off <<= 1) {
        int t = __shfl_up(incl, off);
        if (lane >= off) incl += t;
    }
    __shared__ int wsum[4];
    if (lane == 63) wsum[tid >> 6] = incl;
    __syncthreads();
    int woff = 0;
    const int w = tid >> 6;
    for (int k = 0; k < w; ++k) woff += wsum[k];
    int excl = incl - s + woff + partials[blockIdx.x];
#pragma unroll
    for (int j = 0; j < 4; ++j) {
        int i = i0 + j;
        if (i < n) {
            row_start[i] = excl;
            cursor[i] = excl;
            inv_deg[i] = 1.0f / (float)max(d[j], 1);
            excl += d[j];
        }
    }
}

__global__ void scatter_kernel(const int* __restrict__ idx, int* __restrict__ cursor,
                               int* __restrict__ sorted_src, int E) {
    int i = blockIdx.x * 256 + threadIdx.x;
    if (i < E) {
        int d = idx[E + i];
        int p = atomicAdd(&cursor[d], 1);
        sorted_src[p] = idx[i];
    }
}

// ---- presplit v2: W -> MFMA B-fragment order, split bf16 hi/lo ----
// wfrag[l][plane(4)][chunk(4)][ct(8)][lane(64)][j(8)], plane: 0=Wl-hi,
// 1=Wl-lo, 2=Wr-hi, 3=Wr-lo. Element (lane,j) of (ct,chunk):
// n = ct*16 + (lane&15), k = chunk*32 + (lane>>4)*8 + j  [B-frag, m89/m91].
__global__ __launch_bounds__(256) void presplit_kernel(
    const float* __restrict__ Wl, const float* __restrict__ Wr,
    short* __restrict__ wfrag, int total) {
    int idx = blockIdx.x * 256 + threadIdx.x;
    if (idx >= total) return;
    int j = idx & 7;
    int lane = (idx >> 3) & 63;
    int ct = (idx >> 9) & 7;
    int chunk = (idx >> 12) & 3;
    int plane = (idx >> 14) & 3;
    int l = idx >> 16;
    int nn = ct * 16 + (lane & 15);
    int k = chunk * 32 + (lane >> 4) * 8 + j;
    const float* src = (plane < 2) ? Wl : Wr;
    float v = src[(size_t)l * 16384 + (size_t)k * 128 + nn];
    unsigned short h = f2bf(v);
    wfrag[idx] = (plane & 1) ? (short)f2bf(v - bf2f(h)) : (short)h;
}

// ------- fused aggregate + GEMM (R12) -------
// Phase 1: each block mean-aggregates its own 64 nodes (32-lane-group gather,
// identical inner loop to the old aggregate_kernel) and writes the result
// directly into full-width split-bf16 LDS in MFMA A-fragment row layout
// ([64][136] shorts: 272 B stride = 16B-aligned, same bank spread as the
// proven [64][40]). Kills the 25.6 MB aggr write + 25.6 MB re-read per layer
// and one launch per layer.
// Phase 2: the proven gemm v8 chunk loop; only X restaged per chunk
// (256 threads x 8 floats), Ag fragments read straight from full-width LDS.
// LDS: 34.8 KB (Ag hi/lo) + 10.2 KB (X hi/lo) = 44 KB -> 3 blocks/CU.
__global__ __launch_bounds__(256, 3) void fused_kernel(
    const float* __restrict__ X, const int* __restrict__ row_start,
    const int* __restrict__ sorted_src, const float* __restrict__ inv_deg,
    const short* __restrict__ wfrag,   // this layer's 65536-elem block
    const float* __restrict__ bias, float* __restrict__ Y, int n, int do_relu) {
    __shared__ __align__(16) short sAgh[64][136];
    __shared__ __align__(16) short sAgl[64][136];
    __shared__ __align__(16) short sXh[64][40];
    __shared__ __align__(16) short sXl[64][40];

    const int tid = threadIdx.x;
    const int row0 = blockIdx.x * 64;

    // ---------- Phase 1: gather + mean into LDS (split bf16) ----------
    {
        const int grp = tid >> 5;        // 0..7, each group owns 8 nodes
        const int lane32 = tid & 31;
        const int q = lane32 << 2;       // 4 floats per lane
        for (int u = 0; u < 8; ++u) {
            const int nloc = grp * 8 + u;
            const int node = row0 + nloc;
            float4 acc = make_float4(0.f, 0.f, 0.f, 0.f);
            if (node < n) {
                const int beg = row_start[node];
                const int end = row_start[node + 1];
                for (int base = beg; base < end; base += 32) {
                    const int cnt = min(end - base, 32);
                    const int my_src = (lane32 < cnt) ? sorted_src[base + lane32] : 0;
                    for (int jb = 0; jb < cnt; jb += 8) {
                        float4 v[8];
                        float m[8];
#pragma unroll
                        for (int t = 0; t < 8; ++t) {
                            const int j = jb + t;
                            const int js = (j < cnt) ? j : (cnt - 1);
                            const int s = __shfl(my_src, js, 32);
                            v[t] = *(const float4*)(X + (size_t)s * NDIM + q);
                            m[t] = (j < cnt) ? 1.f : 0.f;
                        }
#pragma unroll
                        for (int t = 0; t < 8; ++t) {
                            acc.x = fmaf(m[t], v[t].x, acc.x);
                            acc.y = fmaf(m[t], v[t].y, acc.y);
                            acc.z = fmaf(m[t], v[t].z, acc.z);
                            acc.w = fmaf(m[t], v[t].w, acc.w);
                        }
                    }
                }
                const float inv = inv_deg[node];
                acc.x *= inv; acc.y *= inv; acc.z *= inv; acc.w *= inv;
            }
            float vv[4] = {acc.x, acc.y, acc.z, acc.w};
            unsigned short h[4], lo[4];
#pragma unroll
            for (int m = 0; m < 4; ++m) {
                h[m] = f2bf(vv[m]);
                lo[m] = f2bf(vv[m] - bf2f(h[m]));
            }
            *(int2*)&sAgh[nloc][q] = make_int2(
                (int)(h[0] | ((unsigned)h[1] << 16)), (int)(h[2] | ((unsigned)h[3] << 16)));
            *(int2*)&sAgl[nloc][q] = make_int2(
                (int)(lo[0] | ((unsigned)lo[1] << 16)), (int)(lo[2] | ((unsigned)lo[3] << 16)));
        }
    }

    // ---------- Phase 2: GEMM ----------
    const int lane = tid & 63;
    const int wave = tid >> 6;
    const int ln15 = lane & 15;
    const int quad = lane >> 4;
    const int wr0 = (wave & 1) * 32;     // wave's row offset
    const int wc0 = (wave >> 1) * 64;    // wave's col offset
    const int ctbase = (wave >> 1) * 4;  // global col-tile base

    f32x4 acc[2][4];
#pragma unroll
    for (int i = 0; i < 2; ++i)
#pragma unroll
        for (int j = 0; j < 4; ++j) acc[i][j] = (f32x4)(0.f);

    // X staging: 256 threads x 8 floats per chunk
    const int xrow = tid >> 2;          // 0..63
    const int xoct = tid & 3;           // 0..3
    int arow = row0 + xrow;
    if (arow >= n) arow = n - 1;
    const float* xsrc = X + (size_t)arow * NDIM + xoct * 8;
    short* xdh = &sXh[xrow][xoct * 8];
    short* xdl = &sXl[xrow][xoct * 8];

    for (int chunk = 0; chunk < 4; ++chunk) {
        const int k0 = chunk * 32;
        float4 f0 = *(const float4*)(xsrc + k0);
        float4 f1 = *(const float4*)(xsrc + k0 + 4);
        __syncthreads();   // chunk 0: also orders phase-1 LDS writes
        {
            float vals[8] = {f0.x, f0.y, f0.z, f0.w, f1.x, f1.y, f1.z, f1.w};
            unsigned short h[8], lo[8];
#pragma unroll
            for (int j = 0; j < 8; ++j) {
                h[j] = f2bf(vals[j]);
                lo[j] = f2bf(vals[j] - bf2f(h[j]));
            }
            *(int4*)xdh = make_int4(
                (int)(h[0] | ((unsigned)h[1] << 16)), (int)(h[2] | ((unsigned)h[3] << 16)),
                (int)(h[4] | ((unsigned)h[5] << 16)), (int)(h[6] | ((unsigned)h[7] << 16)));
            *(int4*)xdl = make_int4(
                (int)(lo[0] | ((unsigned)lo[1] << 16)), (int)(lo[2] | ((unsigned)lo[3] << 16)),
                (int)(lo[4] | ((unsigned)lo[5] << 16)), (int)(lo[6] | ((unsigned)lo[7] << 16)));
        }
        __syncthreads();

        // A fragments: one ds_read_b128 each
        s16x8 fAgh[2], fAgl[2], fXh[2], fXl[2];
#pragma unroll
        for (int rt = 0; rt < 2; ++rt) {
            const int r = wr0 + rt * 16 + ln15;
            fAgh[rt] = *(const s16x8*)&sAgh[r][k0 + quad * 8];
            fAgl[rt] = *(const s16x8*)&sAgl[r][k0 + quad * 8];
            fXh[rt]  = *(const s16x8*)&sXh[r][quad * 8];
            fXl[rt]  = *(const s16x8*)&sXl[r][quad * 8];
        }
#pragma unroll
        for (int ct = 0; ct < 4; ++ct) {
            const short* wb = wfrag + (chunk << 12) + ((ctbase + ct) << 9) + (lane << 3);
            const s16x8 blh = *(const s16x8*)(wb);            // Wl-hi
            const s16x8 bll = *(const s16x8*)(wb + 16384);    // Wl-lo
            const s16x8 brh = *(const s16x8*)(wb + 32768);    // Wr-hi
            const s16x8 brl = *(const s16x8*)(wb + 49152);    // Wr-lo
#pragma unroll
            for (int rt = 0; rt < 2; ++rt) {
                acc[rt][ct] = __builtin_amdgcn_mfma_f32_16x16x32_bf16(fAgh[rt], blh, acc[rt][ct], 0, 0, 0);
                acc[rt][ct] = __builtin_amdgcn_mfma_f32_16x16x32_bf16(fAgh[rt], bll, acc[rt][ct], 0, 0, 0);
                acc[rt][ct] = __builtin_amdgcn_mfma_f32_16x16x32_bf16(fAgl[rt], blh, acc[rt][ct], 0, 0, 0);
                acc[rt][ct] = __builtin_amdgcn_mfma_f32_16x16x32_bf16(fXh[rt],  brh, acc[rt][ct], 0, 0, 0);
                acc[rt][ct] = __builtin_amdgcn_mfma_f32_16x16x32_bf16(fXh[rt],  brl, acc[rt][ct], 0, 0, 0);
                acc[rt][ct] = __builtin_amdgcn_mfma_f32_16x16x32_bf16(fXl[rt],  brh, acc[rt][ct], 0, 0, 0);
            }
        }
    }

    // epilogue: C/D layout col=lane&15, row=quad*4+reg [m89]
#pragma unroll
    for (int rt = 0; rt < 2; ++rt) {
#pragma unroll
        for (int ct = 0; ct < 4; ++ct) {
            const int col = wc0 + ct * 16 + ln15;
            const float bv = bias[col];
#pragma unroll
            for (int r = 0; r < 4; ++r) {
                const int grow = row0 + wr0 + rt * 16 + quad * 4 + r;
                if (grow < n) {
                    float v = acc[rt][ct][r] + bv;
                    if (do_relu) v = fmaxf(v, 0.f);
                    Y[(size_t)grow * NDIM + col] = v;
                }
            }
        }
    }
}

// ---------------- host launcher ----------------
extern "C" void kernel_launch(void* const* d_in, const int* in_sizes, int n_in,
                              void* d_out, int out_size, void* d_ws, size_t ws_size,
                              hipStream_t stream) {
    const float* x0   = (const float*)d_in[0];
    const int*   eraw = (const int*)d_in[1];
    const float* Wl   = (const float*)d_in[2];
    const float* bl   = (const float*)d_in[3];
    const float* Wr   = (const float*)d_in[4];
    float* out = (float*)d_out;

    const int N = in_sizes[0] / NDIM;   // 50000
    const int E = in_sizes[1] / 2;      // 600000

    auto align_up = [](size_t v) { return (v + 255) & ~(size_t)255; };
    char* p = (char*)d_ws;
    int* idx = (int*)p;                 p += align_up((size_t)2 * E * 4);
    int* deg = (int*)p;                 p += align_up((size_t)(N + 1) * 4);
    int* flag = deg + N;
    int* row_start = (int*)p;           p += align_up((size_t)(N + 1) * 4);
    int* cursor = (int*)p;              p += align_up((size_t)N * 4);
    int* ssrc = (int*)p;                p += align_up((size_t)E * 4);
    float* invd = (float*)p;            p += align_up((size_t)N * 4);
    int* partials = (int*)p;            p += align_up((size_t)1024 * 4);
    short* wfrag = (short*)p;           p += align_up((size_t)327680 * 2);
    float* buf0 = (float*)p;            p += align_up((size_t)N * NDIM * 4);
    float* buf1 = (float*)p;            p += align_up((size_t)N * NDIM * 4);

    const int nb = (N + 1023) / 1024;

    hipMemsetAsync(deg, 0, (size_t)N * 4, stream);
    detect_kernel<<<1, 256, 0, stream>>>(eraw, flag, E);
    convert_kernel<<<(2 * E + 255) / 256, 256, 0, stream>>>(eraw, flag, idx, deg, E);
    deg_reduce_kernel<<<nb, 256, 0, stream>>>(deg, partials, N);
    scan_partials_kernel<<<1, 1024, 0, stream>>>(partials, nb, row_start, N);
    deg_downsweep_kernel<<<nb, 256, 0, stream>>>(deg, partials, row_start, cursor, invd, N);
    scatter_kernel<<<(E + 255) / 256, 256, 0, stream>>>(idx, cursor, ssrc, E);
    presplit_kernel<<<1280, 256, 0, stream>>>(Wl, Wr, wfrag, 327680);

    // Fused aggregate+GEMM per layer. Y must differ from X (other blocks
    // gather-read arbitrary X rows), so ping-pong buf0/buf1.
    const float* xin = x0;
    for (int l = 0; l < 5; ++l) {
        float* yo = (l == 4) ? out : ((l & 1) ? buf1 : buf0);
        fused_kernel<<<(N + 63) / 64, 256, 0, stream>>>(
            xin, row_start, ssrc, invd, wfrag + (size_t)l * 65536,
            bl + (size_t)l * NDIM, yo, N, l < 4 ? 1 : 0);
        xin = yo;
    }
}